// Round 1
// baseline (1707.468 us; speedup 1.0000x reference)
//
#include <hip/hip_runtime.h>
#include <math.h>

#define N_NODES 50000
#define N_EDGES 300000
#define IN_CH 128
#define HIDDEN 64
#define OUT_CH 40
#define NUM_LAYERS 4
// heads = 8, d_head = 8, scale = 1/sqrt(8)

__global__ void k_init_deg(float* deg) {
    int n = blockIdx.x * blockDim.x + threadIdx.x;
    if (n < N_NODES) deg[n] = 1.0f;  // self-loop contributes 1
}

__global__ void k_deg_accum(const int* __restrict__ dst, float* deg) {
    int e = blockIdx.x * blockDim.x + threadIdx.x;
    if (e < N_EDGES) atomicAdd(&deg[dst[e]], 1.0f);
}

__global__ void k_dinv(float* deg) {
    int n = blockIdx.x * blockDim.x + threadIdx.x;
    if (n < N_NODES) deg[n] = rsqrtf(deg[n]);  // deg >= 1 always
}

// h = relu(x @ w1 + b1) -> xall[:, 0, :]
__global__ __launch_bounds__(256) void k_h(const float* __restrict__ x,
                                           const float* __restrict__ w1,
                                           const float* __restrict__ b1,
                                           float* __restrict__ xall) {
    __shared__ float w1s[IN_CH * HIDDEN];  // 32 KB
    __shared__ float b1s[HIDDEN];
    __shared__ float rows[4 * IN_CH];
    int tid = threadIdx.x;
    for (int i = tid; i < IN_CH * HIDDEN; i += 256) w1s[i] = w1[i];
    if (tid < HIDDEN) b1s[tid] = b1[tid];
    int wid = tid >> 6, lane = tid & 63;
    int n = blockIdx.x * 4 + wid;
    if (n < N_NODES) {
        rows[wid * IN_CH + lane] = x[(size_t)n * IN_CH + lane];
        rows[wid * IN_CH + 64 + lane] = x[(size_t)n * IN_CH + 64 + lane];
    }
    __syncthreads();
    if (n >= N_NODES) return;
    float acc = 0.f;
#pragma unroll 8
    for (int j = 0; j < IN_CH; ++j)
        acc = fmaf(rows[wid * IN_CH + j], w1s[j * HIDDEN + lane], acc);
    acc += b1s[lane];
    xall[(size_t)n * 320 + lane] = fmaxf(acc, 0.f);
}

// q/k/v projections for one layer. jobs = N*(2L+1); job t: 0 -> q (row L-1),
// 1..L -> k (row t-1), L+1..2L -> v (row t-L-1)
__global__ __launch_bounds__(256) void k_qkv(const float* __restrict__ xall,
                                             const float* __restrict__ wq,
                                             const float* __restrict__ wk,
                                             const float* __restrict__ wv,
                                             float* __restrict__ q,
                                             float* __restrict__ k,
                                             float* __restrict__ v,
                                             int L, int jobs) {
    __shared__ float Ws[3 * HIDDEN * HIDDEN];  // 48 KB
    __shared__ float rows[4 * HIDDEN];
    int tid = threadIdx.x;
    for (int i = tid; i < HIDDEN * HIDDEN; i += 256) {
        Ws[i] = wq[i];
        Ws[HIDDEN * HIDDEN + i] = wk[i];
        Ws[2 * HIDDEN * HIDDEN + i] = wv[i];
    }
    int wid = tid >> 6, lane = tid & 63;
    int j = blockIdx.x * 4 + wid;
    int per = 2 * L + 1;
    int n = 0, t = 0, lx = 0, wsel = 0;
    if (j < jobs) {
        n = j / per;
        t = j - n * per;
        if (t == 0) { lx = L - 1; wsel = 0; }
        else if (t <= L) { lx = t - 1; wsel = 1; }
        else { lx = t - L - 1; wsel = 2; }
        rows[wid * 64 + lane] = xall[(size_t)n * 320 + lx * 64 + lane];
    }
    __syncthreads();
    if (j >= jobs) return;
    const float* W = &Ws[wsel * HIDDEN * HIDDEN];
    float acc = 0.f;
#pragma unroll 8
    for (int jj = 0; jj < 64; ++jj)
        acc = fmaf(rows[wid * 64 + jj], W[jj * 64 + lane], acc);
    float* outp;
    if (wsel == 0) outp = &q[(size_t)n * 64];
    else if (wsel == 1) outp = &k[(size_t)n * 256 + lx * 64];
    else outp = &v[(size_t)n * 256 + lx * 64];
    outp[lane] = acc;
}

// one wave per edge; lane = channel c (head = c>>3, d = c&7)
__global__ __launch_bounds__(256) void k_edge(const int* __restrict__ ei,
                                              const float* __restrict__ dinv,
                                              const float* __restrict__ q,
                                              const float* __restrict__ k,
                                              const float* __restrict__ v,
                                              float* __restrict__ agg, int L) {
    int tid = threadIdx.x;
    int wid = tid >> 6, lane = tid & 63;
    int e = blockIdx.x * 4 + wid;
    const int ET = N_EDGES + N_NODES;
    if (e >= ET) return;
    int s, d;
    if (e < N_EDGES) { s = ei[e]; d = ei[N_EDGES + e]; }
    else { s = d = e - N_EDGES; }
    float nrm = dinv[s] * dinv[d];
    float qc = q[(size_t)d * 64 + lane];
    const float scale = 0.35355339059327373f;  // 1/sqrt(8)
    float sc[4];
#pragma unroll 4
    for (int l = 0; l < 4; ++l) {
        if (l >= L) break;
        float p = qc * k[(size_t)s * 256 + l * 64 + lane];
        p += __shfl_xor(p, 1);
        p += __shfl_xor(p, 2);
        p += __shfl_xor(p, 4);
        sc[l] = p * scale;
    }
    float m = sc[0];
    for (int l = 1; l < L; ++l) m = fmaxf(m, sc[l]);
    float ssum = 0.f;
    for (int l = 0; l < L; ++l) { sc[l] = __expf(sc[l] - m); ssum += sc[l]; }
    float inv = 1.0f / ssum;
    float msg = 0.f;
#pragma unroll 4
    for (int l = 0; l < 4; ++l) {
        if (l >= L) break;
        msg = fmaf(sc[l], v[(size_t)s * 256 + l * 64 + lane], msg);
    }
    msg *= inv * nrm;
    atomicAdd(&agg[(size_t)d * 64 + lane], msg);
}

__global__ void k_append(const float* __restrict__ agg, float* __restrict__ xall, int L) {
    int i = blockIdx.x * blockDim.x + threadIdx.x;
    if (i >= N_NODES * 64) return;
    int n = i >> 6, c = i & 63;
    xall[(size_t)n * 320 + L * 64 + c] = fmaxf(agg[i], 0.f);
}

// logits = xall[:,4] @ w2 + b2; out = log_softmax(logits)
__global__ __launch_bounds__(256) void k_final(const float* __restrict__ xall,
                                               const float* __restrict__ w2,
                                               const float* __restrict__ b2,
                                               float* __restrict__ out) {
    __shared__ float w2s[HIDDEN * OUT_CH];
    __shared__ float b2s[OUT_CH];
    __shared__ float rows[4 * 64];
    int tid = threadIdx.x;
    for (int i = tid; i < HIDDEN * OUT_CH; i += 256) w2s[i] = w2[i];
    if (tid < OUT_CH) b2s[tid] = b2[tid];
    int wid = tid >> 6, lane = tid & 63;
    int n = blockIdx.x * 4 + wid;
    if (n < N_NODES) rows[wid * 64 + lane] = xall[(size_t)n * 320 + 256 + lane];
    __syncthreads();
    if (n >= N_NODES) return;
    float logit = -INFINITY;
    if (lane < OUT_CH) {
        float acc = b2s[lane];
#pragma unroll 8
        for (int j = 0; j < 64; ++j)
            acc = fmaf(rows[wid * 64 + j], w2s[j * OUT_CH + lane], acc);
        logit = acc;
    }
    float m = logit;
    for (int mask = 32; mask; mask >>= 1) m = fmaxf(m, __shfl_xor(m, mask));
    float ex = (lane < OUT_CH) ? __expf(logit - m) : 0.f;
    float ssum = ex;
    for (int mask = 32; mask; mask >>= 1) ssum += __shfl_xor(ssum, mask);
    if (lane < OUT_CH) out[(size_t)n * OUT_CH + lane] = logit - m - logf(ssum);
}

extern "C" void kernel_launch(void* const* d_in, const int* in_sizes, int n_in,
                              void* d_out, int out_size, void* d_ws, size_t ws_size,
                              hipStream_t stream) {
    const float* x  = (const float*)d_in[0];
    const int*   ei = (const int*)d_in[1];
    // d_in[2] = heads (known 8)
    const float* w1 = (const float*)d_in[3];
    const float* b1 = (const float*)d_in[4];
    const float* wq = (const float*)d_in[5];
    const float* wk = (const float*)d_in[6];
    const float* wv = (const float*)d_in[7];
    const float* w2 = (const float*)d_in[8];
    const float* b2 = (const float*)d_in[9];
    float* out = (float*)d_out;

    float* ws   = (float*)d_ws;
    float* dinv = ws;                                  // N
    float* xall = dinv + N_NODES;                      // N*320
    float* q    = xall + (size_t)N_NODES * 320;        // N*64
    float* k    = q    + (size_t)N_NODES * 64;         // N*256
    float* v    = k    + (size_t)N_NODES * 256;        // N*256
    float* agg  = v    + (size_t)N_NODES * 256;        // N*64

    k_init_deg<<<(N_NODES + 255) / 256, 256, 0, stream>>>(dinv);
    k_deg_accum<<<(N_EDGES + 255) / 256, 256, 0, stream>>>(ei + N_EDGES, dinv);
    k_dinv<<<(N_NODES + 255) / 256, 256, 0, stream>>>(dinv);
    k_h<<<(N_NODES + 3) / 4, 256, 0, stream>>>(x, w1, b1, xall);

    for (int i = 0; i < NUM_LAYERS; ++i) {
        int L = i + 1;
        int jobs = N_NODES * (2 * L + 1);
        k_qkv<<<(jobs + 3) / 4, 256, 0, stream>>>(xall, wq + i * 4096, wk + i * 4096,
                                                  wv + i * 4096, q, k, v, L, jobs);
        hipMemsetAsync(agg, 0, (size_t)N_NODES * 64 * sizeof(float), stream);
        int ET = N_EDGES + N_NODES;
        k_edge<<<(ET + 3) / 4, 256, 0, stream>>>(ei, dinv, q, k, v, agg, L);
        k_append<<<(N_NODES * 64 + 255) / 256, 256, 0, stream>>>(agg, xall, L);
    }
    k_final<<<(N_NODES + 3) / 4, 256, 0, stream>>>(xall, w2, b2, out);
}

// Round 2
// 955.205 us; speedup vs baseline: 1.7875x; 1.7875x over previous
//
#include <hip/hip_runtime.h>
#include <math.h>

#define N_NODES 50000
#define N_EDGES 300000
#define IN_CH 128
#define HIDDEN 64
#define OUT_CH 40
#define NUM_LAYERS 4
#define QKV_WPR 2048  // waves per role in k_qkv_reg
// heads = 8, d_head = 8, scale = 1/sqrt(8)

__global__ void k_init_deg(float* deg) {
    int n = blockIdx.x * blockDim.x + threadIdx.x;
    if (n < N_NODES) deg[n] = 1.0f;  // self-loop contributes 1
}

__global__ void k_deg_accum(const int* __restrict__ dst, float* deg) {
    int e = blockIdx.x * blockDim.x + threadIdx.x;
    if (e < N_EDGES) atomicAdd(&deg[dst[e]], 1.0f);
}

__global__ void k_dinv(float* deg) {
    int n = blockIdx.x * blockDim.x + threadIdx.x;
    if (n < N_NODES) deg[n] = rsqrtf(deg[n]);  // deg >= 1 always
}

// h = relu(x @ w1 + b1) -> xall[:, 0, :]
// One wave per row; lane = output channel; w1 column held in 128 VGPRs,
// amortized over N_NODES/grid rows. Row data is wave-uniform broadcast loads.
__global__ __launch_bounds__(64) void k_h_reg(const float* __restrict__ x,
                                              const float* __restrict__ w1,
                                              const float* __restrict__ b1,
                                              float* __restrict__ xall) {
    int lane = threadIdx.x;
    float wcol[IN_CH];
#pragma unroll
    for (int j = 0; j < IN_CH; ++j) wcol[j] = w1[j * HIDDEN + lane];
    float b = b1[lane];
    for (int n = blockIdx.x; n < N_NODES; n += gridDim.x) {
        int roff = __builtin_amdgcn_readfirstlane(n * IN_CH);
        const float4* row = (const float4*)(x + roff);
        float a0 = 0.f, a1 = 0.f, a2 = 0.f, a3 = 0.f;
#pragma unroll
        for (int jc = 0; jc < IN_CH / 4; ++jc) {
            float4 r = row[jc];
            a0 = fmaf(r.x, wcol[jc * 4 + 0], a0);
            a1 = fmaf(r.y, wcol[jc * 4 + 1], a1);
            a2 = fmaf(r.z, wcol[jc * 4 + 2], a2);
            a3 = fmaf(r.w, wcol[jc * 4 + 3], a3);
        }
        float acc = (a0 + a1) + (a2 + a3) + b;
        xall[(size_t)n * 320 + lane] = fmaxf(acc, 0.f);
    }
}

// q/k/v projections, weights in registers. Waves are grouped by role:
// role 0 -> q (input row L-1), 1..L -> k (row role-1), L+1..2L -> v (row role-L-1).
// Each wave loads its 64x64 weight matrix column into 64 VGPRs once, then
// grid-strides over nodes. Inner loop: broadcast row loads + pure v_fma.
__global__ __launch_bounds__(256) void k_qkv_reg(const float* __restrict__ xall,
                                                 const float* __restrict__ wq,
                                                 const float* __restrict__ wk,
                                                 const float* __restrict__ wv,
                                                 float* __restrict__ q,
                                                 float* __restrict__ k,
                                                 float* __restrict__ v, int L) {
    int lane = threadIdx.x & 63;
    int gw = blockIdx.x * 4 + (threadIdx.x >> 6);
    int role = gw / QKV_WPR;
    int slot = gw - role * QKV_WPR;
    const float* W;
    float* dstbase;
    int lx, dststride;
    if (role == 0)      { W = wq; lx = L - 1;        dstbase = q;            dststride = 64; }
    else if (role <= L) { W = wk; lx = role - 1;     dstbase = k + lx * 64;  dststride = 256; }
    else                { W = wv; lx = role - L - 1; dstbase = v + lx * 64;  dststride = 256; }
    float wcol[HIDDEN];
#pragma unroll
    for (int j = 0; j < HIDDEN; ++j) wcol[j] = W[j * HIDDEN + lane];
    for (int n = slot; n < N_NODES; n += QKV_WPR) {
        int roff = __builtin_amdgcn_readfirstlane(n * 320 + lx * 64);
        const float4* row = (const float4*)(xall + roff);
        float a0 = 0.f, a1 = 0.f, a2 = 0.f, a3 = 0.f;
#pragma unroll
        for (int jc = 0; jc < HIDDEN / 4; ++jc) {
            float4 r = row[jc];
            a0 = fmaf(r.x, wcol[jc * 4 + 0], a0);
            a1 = fmaf(r.y, wcol[jc * 4 + 1], a1);
            a2 = fmaf(r.z, wcol[jc * 4 + 2], a2);
            a3 = fmaf(r.w, wcol[jc * 4 + 3], a3);
        }
        dstbase[(size_t)n * dststride + lane] = (a0 + a1) + (a2 + a3);
    }
}

// one wave per edge; lane = channel c (head = c>>3, d = c&7)
__global__ __launch_bounds__(256) void k_edge(const int* __restrict__ ei,
                                              const float* __restrict__ dinv,
                                              const float* __restrict__ q,
                                              const float* __restrict__ k,
                                              const float* __restrict__ v,
                                              float* __restrict__ agg, int L) {
    int tid = threadIdx.x;
    int wid = tid >> 6, lane = tid & 63;
    int e = blockIdx.x * 4 + wid;
    const int ET = N_EDGES + N_NODES;
    if (e >= ET) return;
    int s, d;
    if (e < N_EDGES) { s = ei[e]; d = ei[N_EDGES + e]; }
    else { s = d = e - N_EDGES; }
    float nrm = dinv[s] * dinv[d];
    float qc = q[(size_t)d * 64 + lane];
    const float scale = 0.35355339059327373f;  // 1/sqrt(8)
    float sc[4];
#pragma unroll 4
    for (int l = 0; l < 4; ++l) {
        if (l >= L) break;
        float p = qc * k[(size_t)s * 256 + l * 64 + lane];
        p += __shfl_xor(p, 1);
        p += __shfl_xor(p, 2);
        p += __shfl_xor(p, 4);
        sc[l] = p * scale;
    }
    float m = sc[0];
    for (int l = 1; l < L; ++l) m = fmaxf(m, sc[l]);
    float ssum = 0.f;
    for (int l = 0; l < L; ++l) { sc[l] = __expf(sc[l] - m); ssum += sc[l]; }
    float inv = 1.0f / ssum;
    float msg = 0.f;
#pragma unroll 4
    for (int l = 0; l < 4; ++l) {
        if (l >= L) break;
        msg = fmaf(sc[l], v[(size_t)s * 256 + l * 64 + lane], msg);
    }
    msg *= inv * nrm;
    atomicAdd(&agg[(size_t)d * 64 + lane], msg);
}

__global__ void k_append(const float* __restrict__ agg, float* __restrict__ xall, int L) {
    int i = blockIdx.x * blockDim.x + threadIdx.x;
    if (i >= N_NODES * 64) return;
    int n = i >> 6, c = i & 63;
    xall[(size_t)n * 320 + L * 64 + c] = fmaxf(agg[i], 0.f);
}

// logits = xall[:,4] @ w2 + b2; out = log_softmax(logits)
__global__ __launch_bounds__(256) void k_final(const float* __restrict__ xall,
                                               const float* __restrict__ w2,
                                               const float* __restrict__ b2,
                                               float* __restrict__ out) {
    __shared__ float w2s[HIDDEN * OUT_CH];
    __shared__ float b2s[OUT_CH];
    __shared__ float rows[4 * 64];
    int tid = threadIdx.x;
    for (int i = tid; i < HIDDEN * OUT_CH; i += 256) w2s[i] = w2[i];
    if (tid < OUT_CH) b2s[tid] = b2[tid];
    int wid = tid >> 6, lane = tid & 63;
    int n = blockIdx.x * 4 + wid;
    if (n < N_NODES) rows[wid * 64 + lane] = xall[(size_t)n * 320 + 256 + lane];
    __syncthreads();
    if (n >= N_NODES) return;
    float logit = -INFINITY;
    if (lane < OUT_CH) {
        float acc = b2s[lane];
#pragma unroll 8
        for (int j = 0; j < 64; ++j)
            acc = fmaf(rows[wid * 64 + j], w2s[j * OUT_CH + lane], acc);
        logit = acc;
    }
    float m = logit;
    for (int mask = 32; mask; mask >>= 1) m = fmaxf(m, __shfl_xor(m, mask));
    float ex = (lane < OUT_CH) ? __expf(logit - m) : 0.f;
    float ssum = ex;
    for (int mask = 32; mask; mask >>= 1) ssum += __shfl_xor(ssum, mask);
    if (lane < OUT_CH) out[(size_t)n * OUT_CH + lane] = logit - m - logf(ssum);
}

extern "C" void kernel_launch(void* const* d_in, const int* in_sizes, int n_in,
                              void* d_out, int out_size, void* d_ws, size_t ws_size,
                              hipStream_t stream) {
    const float* x  = (const float*)d_in[0];
    const int*   ei = (const int*)d_in[1];
    // d_in[2] = heads (known 8)
    const float* w1 = (const float*)d_in[3];
    const float* b1 = (const float*)d_in[4];
    const float* wq = (const float*)d_in[5];
    const float* wk = (const float*)d_in[6];
    const float* wv = (const float*)d_in[7];
    const float* w2 = (const float*)d_in[8];
    const float* b2 = (const float*)d_in[9];
    float* out = (float*)d_out;

    float* ws   = (float*)d_ws;
    float* dinv = ws;                                  // N
    float* xall = dinv + N_NODES;                      // N*320
    float* q    = xall + (size_t)N_NODES * 320;        // N*64
    float* k    = q    + (size_t)N_NODES * 64;         // N*256
    float* v    = k    + (size_t)N_NODES * 256;        // N*256
    float* agg  = v    + (size_t)N_NODES * 256;        // N*64

    k_init_deg<<<(N_NODES + 255) / 256, 256, 0, stream>>>(dinv);
    k_deg_accum<<<(N_EDGES + 255) / 256, 256, 0, stream>>>(ei + N_EDGES, dinv);
    k_dinv<<<(N_NODES + 255) / 256, 256, 0, stream>>>(dinv);
    k_h_reg<<<2048, 64, 0, stream>>>(x, w1, b1, xall);

    for (int i = 0; i < NUM_LAYERS; ++i) {
        int L = i + 1;
        int nblk = (2 * L + 1) * (QKV_WPR / 4);
        k_qkv_reg<<<nblk, 256, 0, stream>>>(xall, wq + i * 4096, wk + i * 4096,
                                            wv + i * 4096, q, k, v, L);
        hipMemsetAsync(agg, 0, (size_t)N_NODES * 64 * sizeof(float), stream);
        int ET = N_EDGES + N_NODES;
        k_edge<<<(ET + 3) / 4, 256, 0, stream>>>(ei, dinv, q, k, v, agg, L);
        k_append<<<(N_NODES * 64 + 255) / 256, 256, 0, stream>>>(agg, xall, L);
    }
    k_final<<<(N_NODES + 3) / 4, 256, 0, stream>>>(xall, w2, b2, out);
}

// Round 3
// 499.649 us; speedup vs baseline: 3.4173x; 1.9118x over previous
//
#include <hip/hip_runtime.h>
#include <hip/hip_fp16.h>
#include <math.h>

#define N_NODES 50000
#define N_EDGES 300000
#define E_TOT (N_EDGES + N_NODES)
#define IN_CH 128
#define HIDDEN 64
#define OUT_CH 40
#define NUM_LAYERS 4
#define NCHUNK ((N_NODES + 255) / 256)  // 196
// heads = 8, d_head = 8, scale = 1/sqrt(8)

__global__ void k_count_init(int* count, int* fill) {
    int n = blockIdx.x * blockDim.x + threadIdx.x;
    if (n < N_NODES) { count[n] = 1; fill[n] = 1; }  // slot 0 = self-loop
}

__global__ void k_count(const int* __restrict__ dst, int* count) {
    int e = blockIdx.x * blockDim.x + threadIdx.x;
    if (e < N_EDGES) atomicAdd(&count[dst[e]], 1);
}

__global__ __launch_bounds__(256) void k_scan_a(const int* __restrict__ count,
                                                int* __restrict__ loc,
                                                int* __restrict__ psum) {
    __shared__ int s[256];
    int tid = threadIdx.x;
    int g = blockIdx.x * 256 + tid;
    int v = (g < N_NODES) ? count[g] : 0;
    s[tid] = v;
    __syncthreads();
    for (int off = 1; off < 256; off <<= 1) {
        int t = (tid >= off) ? s[tid - off] : 0;
        __syncthreads();
        s[tid] += t;
        __syncthreads();
    }
    if (g < N_NODES) loc[g] = s[tid] - v;  // exclusive
    if (tid == 255) psum[blockIdx.x] = s[255];
}

__global__ __launch_bounds__(256) void k_scan_b(int* psum) {
    __shared__ int s[256];
    int tid = threadIdx.x;
    int v = (tid < NCHUNK) ? psum[tid] : 0;
    s[tid] = v;
    __syncthreads();
    for (int off = 1; off < 256; off <<= 1) {
        int t = (tid >= off) ? s[tid - off] : 0;
        __syncthreads();
        s[tid] += t;
        __syncthreads();
    }
    if (tid < NCHUNK) psum[tid] = s[tid] - v;  // exclusive
}

__global__ void k_scan_c(const int* __restrict__ count, const int* __restrict__ loc,
                         const int* __restrict__ psum, int* __restrict__ rowptr,
                         float* __restrict__ dinv, int* __restrict__ ssrc,
                         float* __restrict__ snorm) {
    int n = blockIdx.x * blockDim.x + threadIdx.x;
    if (n >= N_NODES) return;
    int rp = loc[n] + psum[n >> 8];
    rowptr[n] = rp;
    float di = rsqrtf((float)count[n]);
    dinv[n] = di;
    ssrc[rp] = n;           // self-loop edge
    snorm[rp] = di * di;
    if (n == 0) rowptr[N_NODES] = E_TOT;
}

__global__ void k_scatter(const int* __restrict__ ei, const int* __restrict__ rowptr,
                          int* __restrict__ fill, const float* __restrict__ dinv,
                          int* __restrict__ ssrc, float* __restrict__ snorm) {
    int e = blockIdx.x * blockDim.x + threadIdx.x;
    if (e >= N_EDGES) return;
    int s = ei[e], d = ei[N_EDGES + e];
    int p = rowptr[d] + atomicAdd(&fill[d], 1);
    ssrc[p] = s;
    snorm[p] = dinv[s] * dinv[d];
}

// h = relu(x @ w1 + b1) -> xall[:, 0, :]; one wave per row, weights in VGPRs
__global__ __launch_bounds__(64) void k_h_reg(const float* __restrict__ x,
                                              const float* __restrict__ w1,
                                              const float* __restrict__ b1,
                                              float* __restrict__ xall) {
    int lane = threadIdx.x;
    float wcol[IN_CH];
#pragma unroll
    for (int j = 0; j < IN_CH; ++j) wcol[j] = w1[j * HIDDEN + lane];
    float b = b1[lane];
    for (int n = blockIdx.x; n < N_NODES; n += gridDim.x) {
        int roff = __builtin_amdgcn_readfirstlane(n * IN_CH);
        const float4* row = (const float4*)(x + roff);
        float a0 = 0.f, a1 = 0.f, a2 = 0.f, a3 = 0.f;
#pragma unroll
        for (int jc = 0; jc < IN_CH / 4; ++jc) {
            float4 r = row[jc];
            a0 = fmaf(r.x, wcol[jc * 4 + 0], a0);
            a1 = fmaf(r.y, wcol[jc * 4 + 1], a1);
            a2 = fmaf(r.z, wcol[jc * 4 + 2], a2);
            a3 = fmaf(r.w, wcol[jc * 4 + 3], a3);
        }
        float acc = (a0 + a1) + (a2 + a3) + b;
        xall[(size_t)n * 320 + lane] = fmaxf(acc, 0.f);
    }
}

// q (fp16) + packed k/v (half2) projections; weights held in VGPRs.
// Waves 0..1023: q role. Waves 1024..1024+L*2048: kv role for row lx.
template <int L>
__global__ __launch_bounds__(256) void k_qkv2(const float* __restrict__ xall,
                                              const float* __restrict__ wq,
                                              const float* __restrict__ wk,
                                              const float* __restrict__ wv,
                                              __half* __restrict__ qh,
                                              __half2* __restrict__ kv) {
    int lane = threadIdx.x & 63;
    int gw = blockIdx.x * 4 + (threadIdx.x >> 6);
    if (gw < 1024) {
        float wcol[HIDDEN];
#pragma unroll
        for (int j = 0; j < HIDDEN; ++j) wcol[j] = wq[j * HIDDEN + lane];
        for (int n = gw; n < N_NODES; n += 1024) {
            int roff = __builtin_amdgcn_readfirstlane(n * 320 + (L - 1) * 64);
            const float4* row = (const float4*)(xall + roff);
            float a0 = 0.f, a1 = 0.f, a2 = 0.f, a3 = 0.f;
#pragma unroll
            for (int jc = 0; jc < HIDDEN / 4; ++jc) {
                float4 r = row[jc];
                a0 = fmaf(r.x, wcol[jc * 4 + 0], a0);
                a1 = fmaf(r.y, wcol[jc * 4 + 1], a1);
                a2 = fmaf(r.z, wcol[jc * 4 + 2], a2);
                a3 = fmaf(r.w, wcol[jc * 4 + 3], a3);
            }
            qh[(size_t)n * 64 + lane] = __float2half((a0 + a1) + (a2 + a3));
        }
    } else {
        int t = gw - 1024;
        int lx = t >> 11;
        int slot = t & 2047;
        float wkc[HIDDEN], wvc[HIDDEN];
#pragma unroll
        for (int j = 0; j < HIDDEN; ++j) {
            wkc[j] = wk[j * HIDDEN + lane];
            wvc[j] = wv[j * HIDDEN + lane];
        }
        for (int n = slot; n < N_NODES; n += 2048) {
            int roff = __builtin_amdgcn_readfirstlane(n * 320 + lx * 64);
            const float4* row = (const float4*)(xall + roff);
            float ka = 0.f, kb = 0.f, va = 0.f, vb = 0.f;
#pragma unroll
            for (int jc = 0; jc < HIDDEN / 4; ++jc) {
                float4 r = row[jc];
                ka = fmaf(r.x, wkc[jc * 4 + 0], ka);
                kb = fmaf(r.y, wkc[jc * 4 + 1], kb);
                ka = fmaf(r.z, wkc[jc * 4 + 2], ka);
                kb = fmaf(r.w, wkc[jc * 4 + 3], kb);
                va = fmaf(r.x, wvc[jc * 4 + 0], va);
                vb = fmaf(r.y, wvc[jc * 4 + 1], vb);
                va = fmaf(r.z, wvc[jc * 4 + 2], va);
                vb = fmaf(r.w, wvc[jc * 4 + 3], vb);
            }
            kv[(size_t)n * (L * 64) + lx * 64 + lane] =
                __floats2half2_rn(ka + kb, va + vb);
        }
    }
}

// CSR edge kernel: one wave per dst node; lane = channel; register accumulate.
template <int L>
__global__ __launch_bounds__(256) void k_edge_csr(const int* __restrict__ rowptr,
                                                  const int* __restrict__ ssrc,
                                                  const float* __restrict__ snorm,
                                                  const __half2* __restrict__ kv,
                                                  const __half* __restrict__ qh,
                                                  float* __restrict__ xall) {
    int tid = threadIdx.x;
    int wid = tid >> 6, lane = tid & 63;
    int d = blockIdx.x * 4 + wid;
    if (d >= N_NODES) return;
    int rs = rowptr[d], re = rowptr[d + 1];
    float qc = __half2float(qh[(size_t)d * 64 + lane]);
    const float scale = 0.35355339059327373f;  // 1/sqrt(8)
    float acc = 0.f;
    for (int base = rs; base < re; base += 64) {
        int nc = min(64, re - base);
        int sv = 0;
        float nv = 0.f;
        if (base + lane < re) {
            sv = ssrc[base + lane];
            nv = snorm[base + lane];
        }
        for (int j = 0; j < nc; ++j) {
            int s = __shfl(sv, j);
            float nrm = __shfl(nv, j);
            const __half2* kvb = kv + (size_t)s * (L * 64) + lane;
            float sc[L], vf[L];
#pragma unroll
            for (int l = 0; l < L; ++l) {
                float2 pf = __half22float2(kvb[l * 64]);
                float p = qc * pf.x;
                p += __shfl_xor(p, 1);
                p += __shfl_xor(p, 2);
                p += __shfl_xor(p, 4);
                sc[l] = p * scale;
                vf[l] = pf.y;
            }
            float m = sc[0];
#pragma unroll
            for (int l = 1; l < L; ++l) m = fmaxf(m, sc[l]);
            float ssum = 0.f;
#pragma unroll
            for (int l = 0; l < L; ++l) { sc[l] = __expf(sc[l] - m); ssum += sc[l]; }
            float msg = 0.f;
#pragma unroll
            for (int l = 0; l < L; ++l) msg = fmaf(sc[l], vf[l], msg);
            acc = fmaf(msg, nrm / ssum, acc);
        }
    }
    xall[(size_t)d * 320 + L * 64 + lane] = fmaxf(acc, 0.f);
}

// logits = xall[:,4] @ w2 + b2; out = log_softmax(logits)
__global__ __launch_bounds__(256) void k_final(const float* __restrict__ xall,
                                               const float* __restrict__ w2,
                                               const float* __restrict__ b2,
                                               float* __restrict__ out) {
    __shared__ float w2s[HIDDEN * OUT_CH];
    __shared__ float b2s[OUT_CH];
    __shared__ float rows[4 * 64];
    int tid = threadIdx.x;
    for (int i = tid; i < HIDDEN * OUT_CH; i += 256) w2s[i] = w2[i];
    if (tid < OUT_CH) b2s[tid] = b2[tid];
    int wid = tid >> 6, lane = tid & 63;
    int n = blockIdx.x * 4 + wid;
    if (n < N_NODES) rows[wid * 64 + lane] = xall[(size_t)n * 320 + 256 + lane];
    __syncthreads();
    if (n >= N_NODES) return;
    float logit = -INFINITY;
    if (lane < OUT_CH) {
        float acc = b2s[lane];
#pragma unroll 8
        for (int j = 0; j < 64; ++j)
            acc = fmaf(rows[wid * 64 + j], w2s[j * OUT_CH + lane], acc);
        logit = acc;
    }
    float m = logit;
    for (int mask = 32; mask; mask >>= 1) m = fmaxf(m, __shfl_xor(m, mask));
    float ex = (lane < OUT_CH) ? __expf(logit - m) : 0.f;
    float ssum = ex;
    for (int mask = 32; mask; mask >>= 1) ssum += __shfl_xor(ssum, mask);
    if (lane < OUT_CH) out[(size_t)n * OUT_CH + lane] = logit - m - logf(ssum);
}

extern "C" void kernel_launch(void* const* d_in, const int* in_sizes, int n_in,
                              void* d_out, int out_size, void* d_ws, size_t ws_size,
                              hipStream_t stream) {
    const float* x  = (const float*)d_in[0];
    const int*   ei = (const int*)d_in[1];
    // d_in[2] = heads (known 8)
    const float* w1 = (const float*)d_in[3];
    const float* b1 = (const float*)d_in[4];
    const float* wq = (const float*)d_in[5];
    const float* wk = (const float*)d_in[6];
    const float* wv = (const float*)d_in[7];
    const float* w2 = (const float*)d_in[8];
    const float* b2 = (const float*)d_in[9];
    float* out = (float*)d_out;

    char* cur = (char*)d_ws;
    auto alloc = [&](size_t bytes) { char* p = cur; cur += (bytes + 255) & ~(size_t)255; return p; };
    float*   dinv   = (float*)alloc(N_NODES * 4);
    float*   xall   = (float*)alloc((size_t)N_NODES * 320 * 4);
    __half*  qh     = (__half*)alloc((size_t)N_NODES * 64 * 2);
    __half2* kv     = (__half2*)alloc((size_t)N_NODES * 256 * 4);  // up to L=4
    int*     count  = (int*)alloc(N_NODES * 4);
    int*     loc    = (int*)alloc(N_NODES * 4);
    int*     psum   = (int*)alloc(256 * 4);
    int*     rowptr = (int*)alloc((N_NODES + 1) * 4);
    int*     fill   = (int*)alloc(N_NODES * 4);
    int*     ssrc   = (int*)alloc((size_t)E_TOT * 4);
    float*   snorm  = (float*)alloc((size_t)E_TOT * 4);

    // CSR build (once)
    k_count_init<<<(N_NODES + 255) / 256, 256, 0, stream>>>(count, fill);
    k_count<<<(N_EDGES + 255) / 256, 256, 0, stream>>>(ei + N_EDGES, count);
    k_scan_a<<<NCHUNK, 256, 0, stream>>>(count, loc, psum);
    k_scan_b<<<1, 256, 0, stream>>>(psum);
    k_scan_c<<<(N_NODES + 255) / 256, 256, 0, stream>>>(count, loc, psum, rowptr,
                                                        dinv, ssrc, snorm);
    k_scatter<<<(N_EDGES + 255) / 256, 256, 0, stream>>>(ei, rowptr, fill, dinv,
                                                         ssrc, snorm);

    k_h_reg<<<4096, 64, 0, stream>>>(x, w1, b1, xall);

    for (int i = 0; i < NUM_LAYERS; ++i) {
        int L = i + 1;
        int qkvblk = 256 + L * 512;
        const float* wqi = wq + i * 4096;
        const float* wki = wk + i * 4096;
        const float* wvi = wv + i * 4096;
        switch (L) {
            case 1:
                k_qkv2<1><<<qkvblk, 256, 0, stream>>>(xall, wqi, wki, wvi, qh, kv);
                k_edge_csr<1><<<(N_NODES + 3) / 4, 256, 0, stream>>>(rowptr, ssrc, snorm, kv, qh, xall);
                break;
            case 2:
                k_qkv2<2><<<qkvblk, 256, 0, stream>>>(xall, wqi, wki, wvi, qh, kv);
                k_edge_csr<2><<<(N_NODES + 3) / 4, 256, 0, stream>>>(rowptr, ssrc, snorm, kv, qh, xall);
                break;
            case 3:
                k_qkv2<3><<<qkvblk, 256, 0, stream>>>(xall, wqi, wki, wvi, qh, kv);
                k_edge_csr<3><<<(N_NODES + 3) / 4, 256, 0, stream>>>(rowptr, ssrc, snorm, kv, qh, xall);
                break;
            default:
                k_qkv2<4><<<qkvblk, 256, 0, stream>>>(xall, wqi, wki, wvi, qh, kv);
                k_edge_csr<4><<<(N_NODES + 3) / 4, 256, 0, stream>>>(rowptr, ssrc, snorm, kv, qh, xall);
                break;
        }
    }
    k_final<<<(N_NODES + 3) / 4, 256, 0, stream>>>(xall, w2, b2, out);
}

// Round 4
// 487.675 us; speedup vs baseline: 3.5012x; 1.0246x over previous
//
#include <hip/hip_runtime.h>
#include <hip/hip_fp16.h>
#include <math.h>

#define N_NODES 50000
#define N_EDGES 300000
#define E_TOT (N_EDGES + N_NODES)
#define IN_CH 128
#define HIDDEN 64
#define OUT_CH 40
#define NUM_LAYERS 4
#define NCHUNK ((N_NODES + 255) / 256)  // 196
#define NTILES (N_NODES / 16)           // 3125 (exact)
#define QKV_NBPR 384
// heads = 8, d_head = 8, scale = 1/sqrt(8)

__global__ void k_count_init(int* count, int* fill) {
    int n = blockIdx.x * blockDim.x + threadIdx.x;
    if (n < N_NODES) { count[n] = 1; fill[n] = 1; }  // slot 0 = self-loop
}

__global__ void k_count(const int* __restrict__ dst, int* count) {
    int e = blockIdx.x * blockDim.x + threadIdx.x;
    if (e < N_EDGES) atomicAdd(&count[dst[e]], 1);
}

__global__ __launch_bounds__(256) void k_scan_a(const int* __restrict__ count,
                                                int* __restrict__ loc,
                                                int* __restrict__ psum) {
    __shared__ int s[256];
    int tid = threadIdx.x;
    int g = blockIdx.x * 256 + tid;
    int v = (g < N_NODES) ? count[g] : 0;
    s[tid] = v;
    __syncthreads();
    for (int off = 1; off < 256; off <<= 1) {
        int t = (tid >= off) ? s[tid - off] : 0;
        __syncthreads();
        s[tid] += t;
        __syncthreads();
    }
    if (g < N_NODES) loc[g] = s[tid] - v;  // exclusive
    if (tid == 255) psum[blockIdx.x] = s[255];
}

__global__ __launch_bounds__(256) void k_scan_b(int* psum) {
    __shared__ int s[256];
    int tid = threadIdx.x;
    int v = (tid < NCHUNK) ? psum[tid] : 0;
    s[tid] = v;
    __syncthreads();
    for (int off = 1; off < 256; off <<= 1) {
        int t = (tid >= off) ? s[tid - off] : 0;
        __syncthreads();
        s[tid] += t;
        __syncthreads();
    }
    if (tid < NCHUNK) psum[tid] = s[tid] - v;  // exclusive
}

__global__ void k_scan_c(const int* __restrict__ count, const int* __restrict__ loc,
                         const int* __restrict__ psum, int* __restrict__ rowptr,
                         float* __restrict__ dinv, int* __restrict__ ssrc,
                         float* __restrict__ snorm) {
    int n = blockIdx.x * blockDim.x + threadIdx.x;
    if (n >= N_NODES) return;
    int rp = loc[n] + psum[n >> 8];
    rowptr[n] = rp;
    float di = rsqrtf((float)count[n]);
    dinv[n] = di;
    ssrc[rp] = n;           // self-loop edge
    snorm[rp] = di * di;
    if (n == 0) rowptr[N_NODES] = E_TOT;
}

__global__ void k_scatter(const int* __restrict__ ei, const int* __restrict__ rowptr,
                          int* __restrict__ fill, const float* __restrict__ dinv,
                          int* __restrict__ ssrc, float* __restrict__ snorm) {
    int e = blockIdx.x * blockDim.x + threadIdx.x;
    if (e >= N_EDGES) return;
    int s = ei[e], d = ei[N_EDGES + e];
    int p = rowptr[d] + atomicAdd(&fill[d], 1);
    ssrc[p] = s;
    snorm[p] = dinv[s] * dinv[d];
}

// h = relu(x @ w1 + b1) -> xall[:, 0, :]
// Weights in VGPRs (lane = out channel); rows staged via LDS (coalesced global,
// broadcast ds_read).
__global__ __launch_bounds__(256) void k_h_lds(const float* __restrict__ x,
                                               const float* __restrict__ w1,
                                               const float* __restrict__ b1,
                                               float* __restrict__ xall) {
    __shared__ float rows[16][IN_CH];
    int tid = threadIdx.x, wid = tid >> 6, lane = tid & 63;
    float wcol[IN_CH];
#pragma unroll
    for (int j = 0; j < IN_CH; ++j) wcol[j] = w1[j * HIDDEN + lane];
    float b = b1[lane];
    for (int t = blockIdx.x; t < NTILES; t += gridDim.x) {
        int n0 = t * 16;
        for (int idx = tid; idx < 512; idx += 256) {
            int rr = idx >> 5, seg = idx & 31;
            *(float4*)&rows[rr][seg * 4] =
                *(const float4*)&x[(size_t)(n0 + rr) * IN_CH + seg * 4];
        }
        __syncthreads();
#pragma unroll
        for (int u = 0; u < 4; ++u) {
            int ln = wid * 4 + u;
            const float4* rp = (const float4*)rows[ln];
            float a0 = 0.f, a1 = 0.f, a2 = 0.f, a3 = 0.f;
#pragma unroll
            for (int jc = 0; jc < IN_CH / 4; ++jc) {
                float4 r = rp[jc];
                a0 = fmaf(r.x, wcol[jc * 4 + 0], a0);
                a1 = fmaf(r.y, wcol[jc * 4 + 1], a1);
                a2 = fmaf(r.z, wcol[jc * 4 + 2], a2);
                a3 = fmaf(r.w, wcol[jc * 4 + 3], a3);
            }
            xall[(size_t)(n0 + ln) * 320 + lane] = fmaxf((a0 + a1) + (a2 + a3) + b, 0.f);
        }
        __syncthreads();
    }
}

// q (fp16) + packed k/v (half2) projections; weights in VGPRs, rows via LDS.
// Block role: blockIdx.x / QKV_NBPR -> 0 = q (row L-1), 1..L = k&v for row role-1.
template <int L>
__global__ __launch_bounds__(256) void k_qkv_lds(const float* __restrict__ xall,
                                                 const float* __restrict__ wq,
                                                 const float* __restrict__ wk,
                                                 const float* __restrict__ wv,
                                                 __half* __restrict__ qh,
                                                 __half2* __restrict__ kv) {
    __shared__ float rows[16][HIDDEN];
    int tid = threadIdx.x, wid = tid >> 6, lane = tid & 63;
    int role = blockIdx.x / QKV_NBPR;
    int bslot = blockIdx.x - role * QKV_NBPR;
    int lx = (role == 0) ? (L - 1) : (role - 1);
    float wc0[HIDDEN], wc1[HIDDEN];
    if (role == 0) {
#pragma unroll
        for (int j = 0; j < HIDDEN; ++j) wc0[j] = wq[j * HIDDEN + lane];
    } else {
#pragma unroll
        for (int j = 0; j < HIDDEN; ++j) {
            wc0[j] = wk[j * HIDDEN + lane];
            wc1[j] = wv[j * HIDDEN + lane];
        }
    }
    for (int t = bslot; t < NTILES; t += QKV_NBPR) {
        int n0 = t * 16;
        {
            int rr = tid >> 4, seg = tid & 15;
            *(float4*)&rows[rr][seg * 4] =
                *(const float4*)&xall[(size_t)(n0 + rr) * 320 + lx * 64 + seg * 4];
        }
        __syncthreads();
#pragma unroll
        for (int u = 0; u < 4; ++u) {
            int ln = wid * 4 + u;
            int n = n0 + ln;
            const float4* rp = (const float4*)rows[ln];
            if (role == 0) {
                float a0 = 0.f, a1 = 0.f, a2 = 0.f, a3 = 0.f;
#pragma unroll
                for (int jc = 0; jc < HIDDEN / 4; ++jc) {
                    float4 r = rp[jc];
                    a0 = fmaf(r.x, wc0[jc * 4 + 0], a0);
                    a1 = fmaf(r.y, wc0[jc * 4 + 1], a1);
                    a2 = fmaf(r.z, wc0[jc * 4 + 2], a2);
                    a3 = fmaf(r.w, wc0[jc * 4 + 3], a3);
                }
                qh[(size_t)n * 64 + lane] = __float2half((a0 + a1) + (a2 + a3));
            } else {
                float ka = 0.f, kb = 0.f, va = 0.f, vb = 0.f;
#pragma unroll
                for (int jc = 0; jc < HIDDEN / 4; ++jc) {
                    float4 r = rp[jc];
                    ka = fmaf(r.x, wc0[jc * 4 + 0], ka);
                    kb = fmaf(r.y, wc0[jc * 4 + 1], kb);
                    ka = fmaf(r.z, wc0[jc * 4 + 2], ka);
                    kb = fmaf(r.w, wc0[jc * 4 + 3], kb);
                    va = fmaf(r.x, wc1[jc * 4 + 0], va);
                    vb = fmaf(r.y, wc1[jc * 4 + 1], vb);
                    va = fmaf(r.z, wc1[jc * 4 + 2], va);
                    vb = fmaf(r.w, wc1[jc * 4 + 3], vb);
                }
                kv[(size_t)n * (L * 64) + lx * 64 + lane] =
                    __floats2half2_rn(ka + kb, va + vb);
            }
        }
        __syncthreads();
    }
}

// CSR edge kernel, 4 edges per wave in parallel: subgroup g (16 lanes) owns
// edge base+g; lane r in subgroup covers channels 4r..4r+3 (head = r>>1).
template <int L>
__global__ __launch_bounds__(256) void k_edge_csr4(const int* __restrict__ rowptr,
                                                   const int* __restrict__ ssrc,
                                                   const float* __restrict__ snorm,
                                                   const __half2* __restrict__ kv,
                                                   const __half* __restrict__ qh,
                                                   float* __restrict__ xall) {
    int tid = threadIdx.x;
    int wid = tid >> 6, lane = tid & 63;
    int g = lane >> 4, r = lane & 15;
    int d = blockIdx.x * 4 + wid;
    if (d >= N_NODES) return;
    int rs = rowptr[d], re = rowptr[d + 1];
    float qcf[4];
    {
        float2 raw = ((const float2*)(qh + (size_t)d * 64))[r];
        const __half2* hp = (const __half2*)&raw;
        float2 q01 = __half22float2(hp[0]);
        float2 q23 = __half22float2(hp[1]);
        qcf[0] = q01.x; qcf[1] = q01.y; qcf[2] = q23.x; qcf[3] = q23.y;
    }
    const float scale = 0.35355339059327373f;  // 1/sqrt(8)
    float acc0 = 0.f, acc1 = 0.f, acc2 = 0.f, acc3 = 0.f;
    for (int base = rs; base < re; base += 4) {
        int eidx = base + g;
        bool valid = eidx < re;
        int s = valid ? ssrc[eidx] : 0;
        float nrm = valid ? snorm[eidx] : 0.f;
        float sc[L], vf[L][4];
#pragma unroll
        for (int l = 0; l < L; ++l) {
            float4 raw = ((const float4*)(kv + (size_t)s * (L * 64) + l * 64))[r];
            const __half2* hp = (const __half2*)&raw;
            float2 a = __half22float2(hp[0]);
            float2 bb = __half22float2(hp[1]);
            float2 c = __half22float2(hp[2]);
            float2 e = __half22float2(hp[3]);
            float p = qcf[0] * a.x;
            p = fmaf(qcf[1], bb.x, p);
            p = fmaf(qcf[2], c.x, p);
            p = fmaf(qcf[3], e.x, p);
            p += __shfl_xor(p, 1);  // full 8-ch head dot for head r>>1
            sc[l] = p * scale;
            vf[l][0] = a.y; vf[l][1] = bb.y; vf[l][2] = c.y; vf[l][3] = e.y;
        }
        float m = sc[0];
#pragma unroll
        for (int l = 1; l < L; ++l) m = fmaxf(m, sc[l]);
        float ssum = 0.f;
#pragma unroll
        for (int l = 0; l < L; ++l) { sc[l] = __expf(sc[l] - m); ssum += sc[l]; }
        float w = __fdividef(nrm, ssum);  // nrm = 0 for invalid lanes
        float m0 = 0.f, m1 = 0.f, m2 = 0.f, m3 = 0.f;
#pragma unroll
        for (int l = 0; l < L; ++l) {
            m0 = fmaf(sc[l], vf[l][0], m0);
            m1 = fmaf(sc[l], vf[l][1], m1);
            m2 = fmaf(sc[l], vf[l][2], m2);
            m3 = fmaf(sc[l], vf[l][3], m3);
        }
        acc0 = fmaf(m0, w, acc0);
        acc1 = fmaf(m1, w, acc1);
        acc2 = fmaf(m2, w, acc2);
        acc3 = fmaf(m3, w, acc3);
    }
    acc0 += __shfl_xor(acc0, 16); acc0 += __shfl_xor(acc0, 32);
    acc1 += __shfl_xor(acc1, 16); acc1 += __shfl_xor(acc1, 32);
    acc2 += __shfl_xor(acc2, 16); acc2 += __shfl_xor(acc2, 32);
    acc3 += __shfl_xor(acc3, 16); acc3 += __shfl_xor(acc3, 32);
    if (lane < 16) {
        float4 o;
        o.x = fmaxf(acc0, 0.f); o.y = fmaxf(acc1, 0.f);
        o.z = fmaxf(acc2, 0.f); o.w = fmaxf(acc3, 0.f);
        ((float4*)(xall + (size_t)d * 320 + L * 64))[r] = o;
    }
}

// logits = xall[:,4] @ w2 + b2; out = log_softmax(logits)
// w2 column in VGPRs (lane < 40), rows via LDS, 16 nodes per tile.
__global__ __launch_bounds__(256) void k_final_lds(const float* __restrict__ xall,
                                                   const float* __restrict__ w2,
                                                   const float* __restrict__ b2,
                                                   float* __restrict__ out) {
    __shared__ float rows[16][HIDDEN];
    int tid = threadIdx.x, wid = tid >> 6, lane = tid & 63;
    int cl = (lane < OUT_CH) ? lane : (OUT_CH - 1);
    float wcol[HIDDEN];
#pragma unroll
    for (int j = 0; j < HIDDEN; ++j) wcol[j] = w2[j * OUT_CH + cl];
    float b = b2[cl];
    for (int t = blockIdx.x; t < NTILES; t += gridDim.x) {
        int n0 = t * 16;
        {
            int rr = tid >> 4, seg = tid & 15;
            *(float4*)&rows[rr][seg * 4] =
                *(const float4*)&xall[(size_t)(n0 + rr) * 320 + 256 + seg * 4];
        }
        __syncthreads();
#pragma unroll
        for (int u = 0; u < 4; ++u) {
            int ln = wid * 4 + u;
            const float4* rp = (const float4*)rows[ln];
            float a0 = 0.f, a1 = 0.f, a2 = 0.f, a3 = 0.f;
#pragma unroll
            for (int jc = 0; jc < HIDDEN / 4; ++jc) {
                float4 r = rp[jc];
                a0 = fmaf(r.x, wcol[jc * 4 + 0], a0);
                a1 = fmaf(r.y, wcol[jc * 4 + 1], a1);
                a2 = fmaf(r.z, wcol[jc * 4 + 2], a2);
                a3 = fmaf(r.w, wcol[jc * 4 + 3], a3);
            }
            float logit = (lane < OUT_CH) ? ((a0 + a1) + (a2 + a3) + b) : -INFINITY;
            float m = logit;
            for (int mask = 32; mask; mask >>= 1) m = fmaxf(m, __shfl_xor(m, mask));
            float ex = (lane < OUT_CH) ? __expf(logit - m) : 0.f;
            float ssum = ex;
            for (int mask = 32; mask; mask >>= 1) ssum += __shfl_xor(ssum, mask);
            if (lane < OUT_CH)
                out[(size_t)(n0 + ln) * OUT_CH + lane] = logit - m - logf(ssum);
        }
        __syncthreads();
    }
}

extern "C" void kernel_launch(void* const* d_in, const int* in_sizes, int n_in,
                              void* d_out, int out_size, void* d_ws, size_t ws_size,
                              hipStream_t stream) {
    const float* x  = (const float*)d_in[0];
    const int*   ei = (const int*)d_in[1];
    // d_in[2] = heads (known 8)
    const float* w1 = (const float*)d_in[3];
    const float* b1 = (const float*)d_in[4];
    const float* wq = (const float*)d_in[5];
    const float* wk = (const float*)d_in[6];
    const float* wv = (const float*)d_in[7];
    const float* w2 = (const float*)d_in[8];
    const float* b2 = (const float*)d_in[9];
    float* out = (float*)d_out;

    char* cur = (char*)d_ws;
    auto alloc = [&](size_t bytes) { char* p = cur; cur += (bytes + 255) & ~(size_t)255; return p; };
    float*   dinv   = (float*)alloc(N_NODES * 4);
    float*   xall   = (float*)alloc((size_t)N_NODES * 320 * 4);
    __half*  qh     = (__half*)alloc((size_t)N_NODES * 64 * 2);
    __half2* kv     = (__half2*)alloc((size_t)N_NODES * 256 * 4);  // up to L=4
    int*     count  = (int*)alloc(N_NODES * 4);
    int*     loc    = (int*)alloc(N_NODES * 4);
    int*     psum   = (int*)alloc(256 * 4);
    int*     rowptr = (int*)alloc((N_NODES + 1) * 4);
    int*     fill   = (int*)alloc(N_NODES * 4);
    int*     ssrc   = (int*)alloc((size_t)E_TOT * 4);
    float*   snorm  = (float*)alloc((size_t)E_TOT * 4);

    // CSR build (once)
    k_count_init<<<(N_NODES + 255) / 256, 256, 0, stream>>>(count, fill);
    k_count<<<(N_EDGES + 255) / 256, 256, 0, stream>>>(ei + N_EDGES, count);
    k_scan_a<<<NCHUNK, 256, 0, stream>>>(count, loc, psum);
    k_scan_b<<<1, 256, 0, stream>>>(psum);
    k_scan_c<<<(N_NODES + 255) / 256, 256, 0, stream>>>(count, loc, psum, rowptr,
                                                        dinv, ssrc, snorm);
    k_scatter<<<(N_EDGES + 255) / 256, 256, 0, stream>>>(ei, rowptr, fill, dinv,
                                                         ssrc, snorm);

    k_h_lds<<<512, 256, 0, stream>>>(x, w1, b1, xall);

    for (int i = 0; i < NUM_LAYERS; ++i) {
        int L = i + 1;
        int qkvblk = (L + 1) * QKV_NBPR;
        const float* wqi = wq + i * 4096;
        const float* wki = wk + i * 4096;
        const float* wvi = wv + i * 4096;
        switch (L) {
            case 1:
                k_qkv_lds<1><<<qkvblk, 256, 0, stream>>>(xall, wqi, wki, wvi, qh, kv);
                k_edge_csr4<1><<<(N_NODES + 3) / 4, 256, 0, stream>>>(rowptr, ssrc, snorm, kv, qh, xall);
                break;
            case 2:
                k_qkv_lds<2><<<qkvblk, 256, 0, stream>>>(xall, wqi, wki, wvi, qh, kv);
                k_edge_csr4<2><<<(N_NODES + 3) / 4, 256, 0, stream>>>(rowptr, ssrc, snorm, kv, qh, xall);
                break;
            case 3:
                k_qkv_lds<3><<<qkvblk, 256, 0, stream>>>(xall, wqi, wki, wvi, qh, kv);
                k_edge_csr4<3><<<(N_NODES + 3) / 4, 256, 0, stream>>>(rowptr, ssrc, snorm, kv, qh, xall);
                break;
            default:
                k_qkv_lds<4><<<qkvblk, 256, 0, stream>>>(xall, wqi, wki, wvi, qh, kv);
                k_edge_csr4<4><<<(N_NODES + 3) / 4, 256, 0, stream>>>(rowptr, ssrc, snorm, kv, qh, xall);
                break;
        }
    }
    k_final_lds<<<512, 256, 0, stream>>>(xall, w2, b2, out);
}

// Round 5
// 486.938 us; speedup vs baseline: 3.5065x; 1.0015x over previous
//
#include <hip/hip_runtime.h>
#include <hip/hip_fp16.h>
#include <math.h>

#define N_NODES 50000
#define N_EDGES 300000
#define E_TOT (N_EDGES + N_NODES)
#define IN_CH 128
#define HIDDEN 64
#define OUT_CH 40
#define NUM_LAYERS 4
#define NCHUNK ((N_NODES + 255) / 256)  // 196
#define NTILES (N_NODES / 16)           // 3125 (exact)
// heads = 8, d_head = 8, scale = 1/sqrt(8)

__global__ void k_count_init(int* count, int* fill) {
    int n = blockIdx.x * blockDim.x + threadIdx.x;
    if (n < N_NODES) { count[n] = 1; fill[n] = 1; }  // slot 0 = self-loop
}

__global__ void k_count(const int* __restrict__ dst, int* count) {
    int e = blockIdx.x * blockDim.x + threadIdx.x;
    if (e < N_EDGES) atomicAdd(&count[dst[e]], 1);
}

__global__ __launch_bounds__(256) void k_scan_a(const int* __restrict__ count,
                                                int* __restrict__ loc,
                                                int* __restrict__ psum) {
    __shared__ int s[256];
    int tid = threadIdx.x;
    int g = blockIdx.x * 256 + tid;
    int v = (g < N_NODES) ? count[g] : 0;
    s[tid] = v;
    __syncthreads();
    for (int off = 1; off < 256; off <<= 1) {
        int t = (tid >= off) ? s[tid - off] : 0;
        __syncthreads();
        s[tid] += t;
        __syncthreads();
    }
    if (g < N_NODES) loc[g] = s[tid] - v;  // exclusive
    if (tid == 255) psum[blockIdx.x] = s[255];
}

__global__ __launch_bounds__(256) void k_scan_b(int* psum) {
    __shared__ int s[256];
    int tid = threadIdx.x;
    int v = (tid < NCHUNK) ? psum[tid] : 0;
    s[tid] = v;
    __syncthreads();
    for (int off = 1; off < 256; off <<= 1) {
        int t = (tid >= off) ? s[tid - off] : 0;
        __syncthreads();
        s[tid] += t;
        __syncthreads();
    }
    if (tid < NCHUNK) psum[tid] = s[tid] - v;  // exclusive
}

__global__ void k_scan_c(const int* __restrict__ count, const int* __restrict__ loc,
                         const int* __restrict__ psum, int* __restrict__ rowptr,
                         float* __restrict__ dinv, int* __restrict__ ssrc,
                         float* __restrict__ snorm) {
    int n = blockIdx.x * blockDim.x + threadIdx.x;
    if (n >= N_NODES) return;
    int rp = loc[n] + psum[n >> 8];
    rowptr[n] = rp;
    float di = rsqrtf((float)count[n]);
    dinv[n] = di;
    ssrc[rp] = n;           // self-loop edge
    snorm[rp] = di * di;
    if (n == 0) rowptr[N_NODES] = E_TOT;
}

__global__ void k_scatter(const int* __restrict__ ei, const int* __restrict__ rowptr,
                          int* __restrict__ fill, const float* __restrict__ dinv,
                          int* __restrict__ ssrc, float* __restrict__ snorm) {
    int e = blockIdx.x * blockDim.x + threadIdx.x;
    if (e >= N_EDGES) return;
    int s = ei[e], d = ei[N_EDGES + e];
    int p = rowptr[d] + atomicAdd(&fill[d], 1);
    ssrc[p] = s;
    snorm[p] = dinv[s] * dinv[d];
}

// h = relu(x @ w1 + b1) -> xall[:, 0, :]; weights in VGPRs, rows via LDS.
__global__ __launch_bounds__(256) void k_h_lds(const float* __restrict__ x,
                                               const float* __restrict__ w1,
                                               const float* __restrict__ b1,
                                               float* __restrict__ xall) {
    __shared__ float rows[16][IN_CH];
    int tid = threadIdx.x, wid = tid >> 6, lane = tid & 63;
    float wcol[IN_CH];
#pragma unroll
    for (int j = 0; j < IN_CH; ++j) wcol[j] = w1[j * HIDDEN + lane];
    float b = b1[lane];
    for (int t = blockIdx.x; t < NTILES; t += gridDim.x) {
        int n0 = t * 16;
        for (int idx = tid; idx < 512; idx += 256) {
            int rr = idx >> 5, seg = idx & 31;
            *(float4*)&rows[rr][seg * 4] =
                *(const float4*)&x[(size_t)(n0 + rr) * IN_CH + seg * 4];
        }
        __syncthreads();
#pragma unroll
        for (int u = 0; u < 4; ++u) {
            int ln = wid * 4 + u;
            const float4* rp = (const float4*)rows[ln];
            float a0 = 0.f, a1 = 0.f, a2 = 0.f, a3 = 0.f;
#pragma unroll
            for (int jc = 0; jc < IN_CH / 4; ++jc) {
                float4 r = rp[jc];
                a0 = fmaf(r.x, wcol[jc * 4 + 0], a0);
                a1 = fmaf(r.y, wcol[jc * 4 + 1], a1);
                a2 = fmaf(r.z, wcol[jc * 4 + 2], a2);
                a3 = fmaf(r.w, wcol[jc * 4 + 3], a3);
            }
            xall[(size_t)(n0 + ln) * 320 + lane] = fmaxf((a0 + a1) + (a2 + a3) + b, 0.f);
        }
        __syncthreads();
    }
}

// Separate-role projections (round-2 structure): 2048 waves per role, 64 weight
// VGPRs, wave-uniform float4 row loads. role 0: q (pre-scaled by 1/sqrt(8));
// 1..L: k row role-1; L+1..2L: v row role-L-1. Outputs fp16.
template <int L>
__global__ __launch_bounds__(256) void k_qkv_sep(const float* __restrict__ xall,
                                                 const float* __restrict__ wq,
                                                 const float* __restrict__ wk,
                                                 const float* __restrict__ wv,
                                                 __half* __restrict__ qh,
                                                 __half* __restrict__ kh,
                                                 __half* __restrict__ vh) {
    int lane = threadIdx.x & 63;
    int gw = blockIdx.x * 4 + (threadIdx.x >> 6);
    int role = gw >> 11;   // 2048 waves per role
    int slot = gw & 2047;
    const float* W;
    int lx;
    __half* outp;
    float scl;
    bool isq = (role == 0);
    if (isq)            { W = wq; lx = L - 1;        outp = qh;           scl = 0.35355339059327373f; }
    else if (role <= L) { W = wk; lx = role - 1;     outp = kh + lx * 64; scl = 1.0f; }
    else                { W = wv; lx = role - L - 1; outp = vh + lx * 64; scl = 1.0f; }
    float wcol[HIDDEN];
#pragma unroll
    for (int j = 0; j < HIDDEN; ++j) wcol[j] = W[j * HIDDEN + lane];
    for (int n = slot; n < N_NODES; n += 2048) {
        int roff = __builtin_amdgcn_readfirstlane(n * 320 + lx * 64);
        const float4* row = (const float4*)(xall + roff);
        float a0 = 0.f, a1 = 0.f, a2 = 0.f, a3 = 0.f;
#pragma unroll
        for (int jc = 0; jc < HIDDEN / 4; ++jc) {
            float4 r = row[jc];
            a0 = fmaf(r.x, wcol[jc * 4 + 0], a0);
            a1 = fmaf(r.y, wcol[jc * 4 + 1], a1);
            a2 = fmaf(r.z, wcol[jc * 4 + 2], a2);
            a3 = fmaf(r.w, wcol[jc * 4 + 3], a3);
        }
        float res = ((a0 + a1) + (a2 + a3)) * scl;
        size_t off = isq ? ((size_t)n * 64) : ((size_t)n * (L * 64));
        outp[off + lane] = __float2half(res);
    }
}

// CSR edge kernel, 8 edges per wave: subgroup g (8 lanes) owns edge base+g;
// lane r owns head r (channels 8r..8r+7). No cross-lane ops in the edge loop.
template <int L>
__global__ __launch_bounds__(256) void k_edge_csr8(const int* __restrict__ rowptr,
                                                   const int* __restrict__ ssrc,
                                                   const float* __restrict__ snorm,
                                                   const __half* __restrict__ kh,
                                                   const __half* __restrict__ vh,
                                                   const __half* __restrict__ qh,
                                                   float* __restrict__ xall) {
    int tid = threadIdx.x;
    int wid = tid >> 6, lane = tid & 63;
    int g = lane >> 3, r = lane & 7;
    int d = blockIdx.x * 4 + wid;
    if (d >= N_NODES) return;
    int rs = rowptr[d], re = rowptr[d + 1];
    float qf[8];
    {
        float4 raw = ((const float4*)(qh + (size_t)d * 64))[r];
        const __half2* hp = (const __half2*)&raw;
#pragma unroll
        for (int i = 0; i < 4; ++i) {
            float2 f = __half22float2(hp[i]);
            qf[2 * i] = f.x; qf[2 * i + 1] = f.y;
        }
    }
    float acc[8];
#pragma unroll
    for (int i = 0; i < 8; ++i) acc[i] = 0.f;
    for (int base = rs; base < re; base += 8) {
        int eidx = base + g;
        bool valid = eidx < re;
        int s = valid ? ssrc[eidx] : 0;
        float nrm = valid ? snorm[eidx] : 0.f;
        float sc[L];
        float4 vraw[L];
#pragma unroll
        for (int l = 0; l < L; ++l) {
            size_t rowo = ((size_t)s * L + l) * 64 + r * 8;
            float4 kraw = *(const float4*)(kh + rowo);
            vraw[l] = *(const float4*)(vh + rowo);
            const __half2* hp = (const __half2*)&kraw;
            float p = 0.f;
#pragma unroll
            for (int i = 0; i < 4; ++i) {
                float2 f = __half22float2(hp[i]);
                p = fmaf(qf[2 * i], f.x, p);
                p = fmaf(qf[2 * i + 1], f.y, p);
            }
            sc[l] = p;
        }
        float m = sc[0];
#pragma unroll
        for (int l = 1; l < L; ++l) m = fmaxf(m, sc[l]);
        float ssum = 0.f;
#pragma unroll
        for (int l = 0; l < L; ++l) { sc[l] = __expf(sc[l] - m); ssum += sc[l]; }
        float w = __fdividef(nrm, ssum);  // 0 for invalid lanes
#pragma unroll
        for (int l = 0; l < L; ++l) {
            float swl = sc[l] * w;
            const __half2* hp = (const __half2*)&vraw[l];
#pragma unroll
            for (int i = 0; i < 4; ++i) {
                float2 f = __half22float2(hp[i]);
                acc[2 * i] = fmaf(swl, f.x, acc[2 * i]);
                acc[2 * i + 1] = fmaf(swl, f.y, acc[2 * i + 1]);
            }
        }
    }
#pragma unroll
    for (int i = 0; i < 8; ++i) {
        acc[i] += __shfl_xor(acc[i], 8);
        acc[i] += __shfl_xor(acc[i], 16);
        acc[i] += __shfl_xor(acc[i], 32);
    }
    if (lane < 8) {  // g==0, r==lane
        float4 o0, o1;
        o0.x = fmaxf(acc[0], 0.f); o0.y = fmaxf(acc[1], 0.f);
        o0.z = fmaxf(acc[2], 0.f); o0.w = fmaxf(acc[3], 0.f);
        o1.x = fmaxf(acc[4], 0.f); o1.y = fmaxf(acc[5], 0.f);
        o1.z = fmaxf(acc[6], 0.f); o1.w = fmaxf(acc[7], 0.f);
        float4* op = (float4*)(xall + (size_t)d * 320 + L * 64);
        op[r * 2] = o0; op[r * 2 + 1] = o1;
    }
}

// logits = xall[:,4] @ w2 + b2; out = log_softmax(logits)
__global__ __launch_bounds__(256) void k_final_lds(const float* __restrict__ xall,
                                                   const float* __restrict__ w2,
                                                   const float* __restrict__ b2,
                                                   float* __restrict__ out) {
    __shared__ float rows[16][HIDDEN];
    int tid = threadIdx.x, wid = tid >> 6, lane = tid & 63;
    int cl = (lane < OUT_CH) ? lane : (OUT_CH - 1);
    float wcol[HIDDEN];
#pragma unroll
    for (int j = 0; j < HIDDEN; ++j) wcol[j] = w2[j * OUT_CH + cl];
    float b = b2[cl];
    for (int t = blockIdx.x; t < NTILES; t += gridDim.x) {
        int n0 = t * 16;
        {
            int rr = tid >> 4, seg = tid & 15;
            *(float4*)&rows[rr][seg * 4] =
                *(const float4*)&xall[(size_t)(n0 + rr) * 320 + 256 + seg * 4];
        }
        __syncthreads();
#pragma unroll
        for (int u = 0; u < 4; ++u) {
            int ln = wid * 4 + u;
            const float4* rp = (const float4*)rows[ln];
            float a0 = 0.f, a1 = 0.f, a2 = 0.f, a3 = 0.f;
#pragma unroll
            for (int jc = 0; jc < HIDDEN / 4; ++jc) {
                float4 r = rp[jc];
                a0 = fmaf(r.x, wcol[jc * 4 + 0], a0);
                a1 = fmaf(r.y, wcol[jc * 4 + 1], a1);
                a2 = fmaf(r.z, wcol[jc * 4 + 2], a2);
                a3 = fmaf(r.w, wcol[jc * 4 + 3], a3);
            }
            float logit = (lane < OUT_CH) ? ((a0 + a1) + (a2 + a3) + b) : -INFINITY;
            float m = logit;
            for (int mask = 32; mask; mask >>= 1) m = fmaxf(m, __shfl_xor(m, mask));
            float ex = (lane < OUT_CH) ? __expf(logit - m) : 0.f;
            float ssum = ex;
            for (int mask = 32; mask; mask >>= 1) ssum += __shfl_xor(ssum, mask);
            if (lane < OUT_CH)
                out[(size_t)(n0 + ln) * OUT_CH + lane] = logit - m - logf(ssum);
        }
        __syncthreads();
    }
}

extern "C" void kernel_launch(void* const* d_in, const int* in_sizes, int n_in,
                              void* d_out, int out_size, void* d_ws, size_t ws_size,
                              hipStream_t stream) {
    const float* x  = (const float*)d_in[0];
    const int*   ei = (const int*)d_in[1];
    // d_in[2] = heads (known 8)
    const float* w1 = (const float*)d_in[3];
    const float* b1 = (const float*)d_in[4];
    const float* wq = (const float*)d_in[5];
    const float* wk = (const float*)d_in[6];
    const float* wv = (const float*)d_in[7];
    const float* w2 = (const float*)d_in[8];
    const float* b2 = (const float*)d_in[9];
    float* out = (float*)d_out;

    char* cur = (char*)d_ws;
    auto alloc = [&](size_t bytes) { char* p = cur; cur += (bytes + 255) & ~(size_t)255; return p; };
    float*   dinv   = (float*)alloc(N_NODES * 4);
    float*   xall   = (float*)alloc((size_t)N_NODES * 320 * 4);
    __half*  qh     = (__half*)alloc((size_t)N_NODES * 64 * 2);
    __half*  kh     = (__half*)alloc((size_t)N_NODES * 256 * 2);  // up to L=4
    __half*  vh     = (__half*)alloc((size_t)N_NODES * 256 * 2);
    int*     count  = (int*)alloc(N_NODES * 4);
    int*     loc    = (int*)alloc(N_NODES * 4);
    int*     psum   = (int*)alloc(256 * 4);
    int*     rowptr = (int*)alloc((N_NODES + 1) * 4);
    int*     fill   = (int*)alloc(N_NODES * 4);
    int*     ssrc   = (int*)alloc((size_t)E_TOT * 4);
    float*   snorm  = (float*)alloc((size_t)E_TOT * 4);

    // CSR build (once)
    k_count_init<<<(N_NODES + 255) / 256, 256, 0, stream>>>(count, fill);
    k_count<<<(N_EDGES + 255) / 256, 256, 0, stream>>>(ei + N_EDGES, count);
    k_scan_a<<<NCHUNK, 256, 0, stream>>>(count, loc, psum);
    k_scan_b<<<1, 256, 0, stream>>>(psum);
    k_scan_c<<<(N_NODES + 255) / 256, 256, 0, stream>>>(count, loc, psum, rowptr,
                                                        dinv, ssrc, snorm);
    k_scatter<<<(N_EDGES + 255) / 256, 256, 0, stream>>>(ei, rowptr, fill, dinv,
                                                         ssrc, snorm);

    k_h_lds<<<512, 256, 0, stream>>>(x, w1, b1, xall);

    for (int i = 0; i < NUM_LAYERS; ++i) {
        int L = i + 1;
        int qkvblk = (2 * L + 1) * 512;  // 2048 waves per role
        const float* wqi = wq + i * 4096;
        const float* wki = wk + i * 4096;
        const float* wvi = wv + i * 4096;
        switch (L) {
            case 1:
                k_qkv_sep<1><<<qkvblk, 256, 0, stream>>>(xall, wqi, wki, wvi, qh, kh, vh);
                k_edge_csr8<1><<<(N_NODES + 3) / 4, 256, 0, stream>>>(rowptr, ssrc, snorm, kh, vh, qh, xall);
                break;
            case 2:
                k_qkv_sep<2><<<qkvblk, 256, 0, stream>>>(xall, wqi, wki, wvi, qh, kh, vh);
                k_edge_csr8<2><<<(N_NODES + 3) / 4, 256, 0, stream>>>(rowptr, ssrc, snorm, kh, vh, qh, xall);
                break;
            case 3:
                k_qkv_sep<3><<<qkvblk, 256, 0, stream>>>(xall, wqi, wki, wvi, qh, kh, vh);
                k_edge_csr8<3><<<(N_NODES + 3) / 4, 256, 0, stream>>>(rowptr, ssrc, snorm, kh, vh, qh, xall);
                break;
            default:
                k_qkv_sep<4><<<qkvblk, 256, 0, stream>>>(xall, wqi, wki, wvi, qh, kh, vh);
                k_edge_csr8<4><<<(N_NODES + 3) / 4, 256, 0, stream>>>(rowptr, ssrc, snorm, kh, vh, qh, xall);
                break;
        }
    }
    k_final_lds<<<512, 256, 0, stream>>>(xall, w2, b2, out);
}

// Round 6
// 301.118 us; speedup vs baseline: 5.6704x; 1.6171x over previous
//
#include <hip/hip_runtime.h>
#include <hip/hip_fp16.h>
#include <math.h>

#define N_NODES 50000
#define N_EDGES 300000
#define E_TOT (N_EDGES + N_NODES)
#define IN_CH 128
#define HIDDEN 64
#define OUT_CH 40
#define NUM_LAYERS 4
#define NCHUNK ((N_NODES + 255) / 256)  // 196
#define NTILES (N_NODES / 16)           // 3125 (exact)
#define QKV_WPR 512                     // waves per role in k_qkv_mfma
// heads = 8, d_head = 8, scale = 1/sqrt(8)

typedef _Float16 h8 __attribute__((ext_vector_type(8)));
typedef float f32x4 __attribute__((ext_vector_type(4)));

#define MFMA16(a, b, c) __builtin_amdgcn_mfma_f32_16x16x32_f16((a), (b), (c), 0, 0, 0)

__global__ void k_count_init(int* count, int* fill) {
    int n = blockIdx.x * blockDim.x + threadIdx.x;
    if (n < N_NODES) { count[n] = 1; fill[n] = 1; }  // slot 0 = self-loop
}

__global__ void k_count(const int* __restrict__ dst, int* count) {
    int e = blockIdx.x * blockDim.x + threadIdx.x;
    if (e < N_EDGES) atomicAdd(&count[dst[e]], 1);
}

__global__ __launch_bounds__(256) void k_scan_a(const int* __restrict__ count,
                                                int* __restrict__ loc,
                                                int* __restrict__ psum) {
    __shared__ int s[256];
    int tid = threadIdx.x;
    int g = blockIdx.x * 256 + tid;
    int v = (g < N_NODES) ? count[g] : 0;
    s[tid] = v;
    __syncthreads();
    for (int off = 1; off < 256; off <<= 1) {
        int t = (tid >= off) ? s[tid - off] : 0;
        __syncthreads();
        s[tid] += t;
        __syncthreads();
    }
    if (g < N_NODES) loc[g] = s[tid] - v;  // exclusive
    if (tid == 255) psum[blockIdx.x] = s[255];
}

__global__ __launch_bounds__(256) void k_scan_b(int* psum) {
    __shared__ int s[256];
    int tid = threadIdx.x;
    int v = (tid < NCHUNK) ? psum[tid] : 0;
    s[tid] = v;
    __syncthreads();
    for (int off = 1; off < 256; off <<= 1) {
        int t = (tid >= off) ? s[tid - off] : 0;
        __syncthreads();
        s[tid] += t;
        __syncthreads();
    }
    if (tid < NCHUNK) psum[tid] = s[tid] - v;  // exclusive
}

__global__ void k_scan_c(const int* __restrict__ count, const int* __restrict__ loc,
                         const int* __restrict__ psum, int* __restrict__ rowptr,
                         float* __restrict__ dinv, int* __restrict__ ssrc,
                         float* __restrict__ snorm) {
    int n = blockIdx.x * blockDim.x + threadIdx.x;
    if (n >= N_NODES) return;
    int rp = loc[n] + psum[n >> 8];
    rowptr[n] = rp;
    float di = rsqrtf((float)count[n]);
    dinv[n] = di;
    ssrc[rp] = n;           // self-loop edge
    snorm[rp] = di * di;
    if (n == 0) rowptr[N_NODES] = E_TOT;
}

__global__ void k_scatter(const int* __restrict__ ei, const int* __restrict__ rowptr,
                          int* __restrict__ fill, const float* __restrict__ dinv,
                          int* __restrict__ ssrc, float* __restrict__ snorm) {
    int e = blockIdx.x * blockDim.x + threadIdx.x;
    if (e >= N_EDGES) return;
    int s = ei[e], d = ei[N_EDGES + e];
    int p = rowptr[d] + atomicAdd(&fill[d], 1);
    ssrc[p] = s;
    snorm[p] = dinv[s] * dinv[d];
}

__device__ __forceinline__ h8 load_bfrag(const float* __restrict__ W, int ncols,
                                         int kbase, int c) {
    h8 r;
#pragma unroll
    for (int i = 0; i < 8; ++i) r[i] = (_Float16)W[(kbase + i) * ncols + c];
    return r;
}

// h = relu(x @ w1 + b1) -> xall[:,0,:] (fp32) and xh[:,0,:] (fp16), via MFMA.
// Wave computes 16-node tiles; W1 held as 16 B-fragments (64 VGPRs fp16).
__global__ __launch_bounds__(256) void k_h_mfma(const float* __restrict__ x,
                                                const float* __restrict__ w1,
                                                const float* __restrict__ b1,
                                                float* __restrict__ xall,
                                                __half* __restrict__ xh) {
    int lane = threadIdx.x & 63;
    int gw = blockIdx.x * 4 + (threadIdx.x >> 6);
    int krow = lane >> 4, col = lane & 15;
    h8 B[4][4];
#pragma unroll
    for (int ct = 0; ct < 4; ++ct)
#pragma unroll
        for (int s = 0; s < 4; ++s)
            B[ct][s] = load_bfrag(w1, HIDDEN, krow * 8 + 32 * s, ct * 16 + col);
    float bias[4];
#pragma unroll
    for (int ct = 0; ct < 4; ++ct) bias[ct] = b1[ct * 16 + col];
    for (int t = gw; t < NTILES; t += 1024) {
        int n0 = t * 16;
        const float* xrow = x + (size_t)(n0 + col) * IN_CH + krow * 8;
        f32x4 acc[4] = {{0.f, 0.f, 0.f, 0.f}, {0.f, 0.f, 0.f, 0.f},
                        {0.f, 0.f, 0.f, 0.f}, {0.f, 0.f, 0.f, 0.f}};
#pragma unroll
        for (int s = 0; s < 4; ++s) {
            float4 p0 = *(const float4*)(xrow + 32 * s);
            float4 p1 = *(const float4*)(xrow + 32 * s + 4);
            h8 a;
            a[0] = (_Float16)p0.x; a[1] = (_Float16)p0.y;
            a[2] = (_Float16)p0.z; a[3] = (_Float16)p0.w;
            a[4] = (_Float16)p1.x; a[5] = (_Float16)p1.y;
            a[6] = (_Float16)p1.z; a[7] = (_Float16)p1.w;
#pragma unroll
            for (int ct = 0; ct < 4; ++ct) acc[ct] = MFMA16(a, B[ct][s], acc[ct]);
        }
#pragma unroll
        for (int ct = 0; ct < 4; ++ct)
#pragma unroll
            for (int reg = 0; reg < 4; ++reg) {
                float v = fmaxf(acc[ct][reg] + bias[ct], 0.f);
                size_t o = (size_t)(n0 + krow * 4 + reg) * 320 + ct * 16 + col;
                xall[o] = v;
                xh[o] = __float2half(v);
            }
    }
}

// q / merged-kv projections via MFMA. role 0: q (input row L-1, pre-scaled by
// 1/sqrt(8)); role 1..L: k & v for input row role-1 (one A-load, 16 MFMAs).
template <int L>
__global__ __launch_bounds__(256) void k_qkv_mfma(const __half* __restrict__ xh,
                                                  const float* __restrict__ wq,
                                                  const float* __restrict__ wk,
                                                  const float* __restrict__ wv,
                                                  __half* __restrict__ qh,
                                                  __half* __restrict__ kh,
                                                  __half* __restrict__ vh) {
    int lane = threadIdx.x & 63;
    int gw = blockIdx.x * 4 + (threadIdx.x >> 6);
    int role = gw / QKV_WPR;
    int slot = gw - role * QKV_WPR;
    int krow = lane >> 4, col = lane & 15;
    if (role == 0) {
        int lx = L - 1;
        h8 B[4][2];
#pragma unroll
        for (int ct = 0; ct < 4; ++ct)
#pragma unroll
            for (int s = 0; s < 2; ++s)
                B[ct][s] = load_bfrag(wq, HIDDEN, krow * 8 + 32 * s, ct * 16 + col);
        for (int t = slot; t < NTILES; t += QKV_WPR) {
            int n0 = t * 16;
            const __half* ap = xh + (size_t)(n0 + col) * 320 + lx * 64 + krow * 8;
            h8 a0 = *(const h8*)(const void*)ap;
            h8 a1 = *(const h8*)(const void*)(ap + 32);
            f32x4 acc[4] = {{0.f, 0.f, 0.f, 0.f}, {0.f, 0.f, 0.f, 0.f},
                            {0.f, 0.f, 0.f, 0.f}, {0.f, 0.f, 0.f, 0.f}};
#pragma unroll
            for (int ct = 0; ct < 4; ++ct) {
                acc[ct] = MFMA16(a0, B[ct][0], acc[ct]);
                acc[ct] = MFMA16(a1, B[ct][1], acc[ct]);
            }
#pragma unroll
            for (int ct = 0; ct < 4; ++ct)
#pragma unroll
                for (int reg = 0; reg < 4; ++reg)
                    qh[(size_t)(n0 + krow * 4 + reg) * 64 + ct * 16 + col] =
                        __float2half(acc[ct][reg] * 0.35355339059327373f);
        }
    } else {
        int lx = role - 1;
        h8 Bk[4][2], Bv[4][2];
#pragma unroll
        for (int ct = 0; ct < 4; ++ct)
#pragma unroll
            for (int s = 0; s < 2; ++s) {
                Bk[ct][s] = load_bfrag(wk, HIDDEN, krow * 8 + 32 * s, ct * 16 + col);
                Bv[ct][s] = load_bfrag(wv, HIDDEN, krow * 8 + 32 * s, ct * 16 + col);
            }
        for (int t = slot; t < NTILES; t += QKV_WPR) {
            int n0 = t * 16;
            const __half* ap = xh + (size_t)(n0 + col) * 320 + lx * 64 + krow * 8;
            h8 a0 = *(const h8*)(const void*)ap;
            h8 a1 = *(const h8*)(const void*)(ap + 32);
            f32x4 ak[4] = {{0.f, 0.f, 0.f, 0.f}, {0.f, 0.f, 0.f, 0.f},
                           {0.f, 0.f, 0.f, 0.f}, {0.f, 0.f, 0.f, 0.f}};
            f32x4 av[4] = {{0.f, 0.f, 0.f, 0.f}, {0.f, 0.f, 0.f, 0.f},
                           {0.f, 0.f, 0.f, 0.f}, {0.f, 0.f, 0.f, 0.f}};
#pragma unroll
            for (int ct = 0; ct < 4; ++ct) {
                ak[ct] = MFMA16(a0, Bk[ct][0], ak[ct]);
                ak[ct] = MFMA16(a1, Bk[ct][1], ak[ct]);
                av[ct] = MFMA16(a0, Bv[ct][0], av[ct]);
                av[ct] = MFMA16(a1, Bv[ct][1], av[ct]);
            }
#pragma unroll
            for (int ct = 0; ct < 4; ++ct)
#pragma unroll
                for (int reg = 0; reg < 4; ++reg) {
                    size_t o = (size_t)(n0 + krow * 4 + reg) * (L * 64) + lx * 64 +
                               ct * 16 + col;
                    kh[o] = __float2half(ak[ct][reg]);
                    vh[o] = __float2half(av[ct][reg]);
                }
        }
    }
}

// CSR edge kernel, 8 edges per wave: subgroup g (8 lanes) owns edge base+g;
// lane r owns head r (channels 8r..8r+7). No cross-lane ops in the edge loop.
template <int L>
__global__ __launch_bounds__(256) void k_edge_csr8(const int* __restrict__ rowptr,
                                                   const int* __restrict__ ssrc,
                                                   const float* __restrict__ snorm,
                                                   const __half* __restrict__ kh,
                                                   const __half* __restrict__ vh,
                                                   const __half* __restrict__ qh,
                                                   float* __restrict__ xall,
                                                   __half* __restrict__ xh) {
    int tid = threadIdx.x;
    int wid = tid >> 6, lane = tid & 63;
    int g = lane >> 3, r = lane & 7;
    int d = blockIdx.x * 4 + wid;
    if (d >= N_NODES) return;
    int rs = rowptr[d], re = rowptr[d + 1];
    float qf[8];
    {
        float4 raw = ((const float4*)(qh + (size_t)d * 64))[r];
        const __half2* hp = (const __half2*)&raw;
#pragma unroll
        for (int i = 0; i < 4; ++i) {
            float2 f = __half22float2(hp[i]);
            qf[2 * i] = f.x; qf[2 * i + 1] = f.y;
        }
    }
    float acc[8];
#pragma unroll
    for (int i = 0; i < 8; ++i) acc[i] = 0.f;
    for (int base = rs; base < re; base += 8) {
        int eidx = base + g;
        bool valid = eidx < re;
        int s = valid ? ssrc[eidx] : 0;
        float nrm = valid ? snorm[eidx] : 0.f;
        float sc[L];
        float4 vraw[L];
#pragma unroll
        for (int l = 0; l < L; ++l) {
            size_t rowo = ((size_t)s * L + l) * 64 + r * 8;
            float4 kraw = *(const float4*)(kh + rowo);
            vraw[l] = *(const float4*)(vh + rowo);
            const __half2* hp = (const __half2*)&kraw;
            float p = 0.f;
#pragma unroll
            for (int i = 0; i < 4; ++i) {
                float2 f = __half22float2(hp[i]);
                p = fmaf(qf[2 * i], f.x, p);
                p = fmaf(qf[2 * i + 1], f.y, p);
            }
            sc[l] = p;
        }
        float m = sc[0];
#pragma unroll
        for (int l = 1; l < L; ++l) m = fmaxf(m, sc[l]);
        float ssum = 0.f;
#pragma unroll
        for (int l = 0; l < L; ++l) { sc[l] = __expf(sc[l] - m); ssum += sc[l]; }
        float w = __fdividef(nrm, ssum);  // 0 for invalid lanes
#pragma unroll
        for (int l = 0; l < L; ++l) {
            float swl = sc[l] * w;
            const __half2* hp = (const __half2*)&vraw[l];
#pragma unroll
            for (int i = 0; i < 4; ++i) {
                float2 f = __half22float2(hp[i]);
                acc[2 * i] = fmaf(swl, f.x, acc[2 * i]);
                acc[2 * i + 1] = fmaf(swl, f.y, acc[2 * i + 1]);
            }
        }
    }
#pragma unroll
    for (int i = 0; i < 8; ++i) {
        acc[i] += __shfl_xor(acc[i], 8);
        acc[i] += __shfl_xor(acc[i], 16);
        acc[i] += __shfl_xor(acc[i], 32);
    }
    if (lane < 8) {  // g==0, r==lane
        float4 o0, o1;
        o0.x = fmaxf(acc[0], 0.f); o0.y = fmaxf(acc[1], 0.f);
        o0.z = fmaxf(acc[2], 0.f); o0.w = fmaxf(acc[3], 0.f);
        o1.x = fmaxf(acc[4], 0.f); o1.y = fmaxf(acc[5], 0.f);
        o1.z = fmaxf(acc[6], 0.f); o1.w = fmaxf(acc[7], 0.f);
        float4* op = (float4*)(xall + (size_t)d * 320 + L * 64);
        op[r * 2] = o0; op[r * 2 + 1] = o1;
        __half hbuf[8];
        hbuf[0] = __float2half(o0.x); hbuf[1] = __float2half(o0.y);
        hbuf[2] = __float2half(o0.z); hbuf[3] = __float2half(o0.w);
        hbuf[4] = __float2half(o1.x); hbuf[5] = __float2half(o1.y);
        hbuf[6] = __float2half(o1.z); hbuf[7] = __float2half(o1.w);
        *(float4*)(xh + (size_t)d * 320 + L * 64 + r * 8) = *(float4*)hbuf;
    }
}

// logits = xall[:,4] @ w2 + b2; out = log_softmax(logits)
__global__ __launch_bounds__(256) void k_final_lds(const float* __restrict__ xall,
                                                   const float* __restrict__ w2,
                                                   const float* __restrict__ b2,
                                                   float* __restrict__ out) {
    __shared__ float rows[16][HIDDEN];
    int tid = threadIdx.x, wid = tid >> 6, lane = tid & 63;
    int cl = (lane < OUT_CH) ? lane : (OUT_CH - 1);
    float wcol[HIDDEN];
#pragma unroll
    for (int j = 0; j < HIDDEN; ++j) wcol[j] = w2[j * OUT_CH + cl];
    float b = b2[cl];
    for (int t = blockIdx.x; t < NTILES; t += gridDim.x) {
        int n0 = t * 16;
        {
            int rr = tid >> 4, seg = tid & 15;
            *(float4*)&rows[rr][seg * 4] =
                *(const float4*)&xall[(size_t)(n0 + rr) * 320 + 256 + seg * 4];
        }
        __syncthreads();
#pragma unroll
        for (int u = 0; u < 4; ++u) {
            int ln = wid * 4 + u;
            const float4* rp = (const float4*)rows[ln];
            float a0 = 0.f, a1 = 0.f, a2 = 0.f, a3 = 0.f;
#pragma unroll
            for (int jc = 0; jc < HIDDEN / 4; ++jc) {
                float4 r = rp[jc];
                a0 = fmaf(r.x, wcol[jc * 4 + 0], a0);
                a1 = fmaf(r.y, wcol[jc * 4 + 1], a1);
                a2 = fmaf(r.z, wcol[jc * 4 + 2], a2);
                a3 = fmaf(r.w, wcol[jc * 4 + 3], a3);
            }
            float logit = (lane < OUT_CH) ? ((a0 + a1) + (a2 + a3) + b) : -INFINITY;
            float m = logit;
            for (int mask = 32; mask; mask >>= 1) m = fmaxf(m, __shfl_xor(m, mask));
            float ex = (lane < OUT_CH) ? __expf(logit - m) : 0.f;
            float ssum = ex;
            for (int mask = 32; mask; mask >>= 1) ssum += __shfl_xor(ssum, mask);
            if (lane < OUT_CH)
                out[(size_t)(n0 + ln) * OUT_CH + lane] = logit - m - logf(ssum);
        }
        __syncthreads();
    }
}

extern "C" void kernel_launch(void* const* d_in, const int* in_sizes, int n_in,
                              void* d_out, int out_size, void* d_ws, size_t ws_size,
                              hipStream_t stream) {
    const float* x  = (const float*)d_in[0];
    const int*   ei = (const int*)d_in[1];
    // d_in[2] = heads (known 8)
    const float* w1 = (const float*)d_in[3];
    const float* b1 = (const float*)d_in[4];
    const float* wq = (const float*)d_in[5];
    const float* wk = (const float*)d_in[6];
    const float* wv = (const float*)d_in[7];
    const float* w2 = (const float*)d_in[8];
    const float* b2 = (const float*)d_in[9];
    float* out = (float*)d_out;

    char* cur = (char*)d_ws;
    auto alloc = [&](size_t bytes) { char* p = cur; cur += (bytes + 255) & ~(size_t)255; return p; };
    float*   dinv   = (float*)alloc(N_NODES * 4);
    float*   xall   = (float*)alloc((size_t)N_NODES * 320 * 4);
    __half*  xh     = (__half*)alloc((size_t)N_NODES * 320 * 2);
    __half*  qh     = (__half*)alloc((size_t)N_NODES * 64 * 2);
    __half*  kh     = (__half*)alloc((size_t)N_NODES * 256 * 2);  // up to L=4
    __half*  vh     = (__half*)alloc((size_t)N_NODES * 256 * 2);
    int*     count  = (int*)alloc(N_NODES * 4);
    int*     loc    = (int*)alloc(N_NODES * 4);
    int*     psum   = (int*)alloc(256 * 4);
    int*     rowptr = (int*)alloc((N_NODES + 1) * 4);
    int*     fill   = (int*)alloc(N_NODES * 4);
    int*     ssrc   = (int*)alloc((size_t)E_TOT * 4);
    float*   snorm  = (float*)alloc((size_t)E_TOT * 4);

    // CSR build (once)
    k_count_init<<<(N_NODES + 255) / 256, 256, 0, stream>>>(count, fill);
    k_count<<<(N_EDGES + 255) / 256, 256, 0, stream>>>(ei + N_EDGES, count);
    k_scan_a<<<NCHUNK, 256, 0, stream>>>(count, loc, psum);
    k_scan_b<<<1, 256, 0, stream>>>(psum);
    k_scan_c<<<(N_NODES + 255) / 256, 256, 0, stream>>>(count, loc, psum, rowptr,
                                                        dinv, ssrc, snorm);
    k_scatter<<<(N_EDGES + 255) / 256, 256, 0, stream>>>(ei, rowptr, fill, dinv,
                                                         ssrc, snorm);

    k_h_mfma<<<256, 256, 0, stream>>>(x, w1, b1, xall, xh);

    for (int i = 0; i < NUM_LAYERS; ++i) {
        int L = i + 1;
        int qkvblk = (L + 1) * (QKV_WPR / 4);
        const float* wqi = wq + i * 4096;
        const float* wki = wk + i * 4096;
        const float* wvi = wv + i * 4096;
        switch (L) {
            case 1:
                k_qkv_mfma<1><<<qkvblk, 256, 0, stream>>>(xh, wqi, wki, wvi, qh, kh, vh);
                k_edge_csr8<1><<<(N_NODES + 3) / 4, 256, 0, stream>>>(rowptr, ssrc, snorm, kh, vh, qh, xall, xh);
                break;
            case 2:
                k_qkv_mfma<2><<<qkvblk, 256, 0, stream>>>(xh, wqi, wki, wvi, qh, kh, vh);
                k_edge_csr8<2><<<(N_NODES + 3) / 4, 256, 0, stream>>>(rowptr, ssrc, snorm, kh, vh, qh, xall, xh);
                break;
            case 3:
                k_qkv_mfma<3><<<qkvblk, 256, 0, stream>>>(xh, wqi, wki, wvi, qh, kh, vh);
                k_edge_csr8<3><<<(N_NODES + 3) / 4, 256, 0, stream>>>(rowptr, ssrc, snorm, kh, vh, qh, xall, xh);
                break;
            default:
                k_qkv_mfma<4><<<qkvblk, 256, 0, stream>>>(xh, wqi, wki, wvi, qh, kh, vh);
                k_edge_csr8<4><<<(N_NODES + 3) / 4, 256, 0, stream>>>(rowptr, ssrc, snorm, kh, vh, qh, xall, xh);
                break;
        }
    }
    k_final_lds<<<512, 256, 0, stream>>>(xall, w2, b2, out);
}